// Round 2
// baseline (1546.574 us; speedup 1.0000x reference)
//
#include <hip/hip_runtime.h>

typedef __attribute__((ext_vector_type(8))) short short8;
typedef __attribute__((ext_vector_type(4))) float floatx4;

__device__ __forceinline__ float bf2f(unsigned short u) {
    unsigned int v = ((unsigned int)u) << 16;
    return __builtin_bit_cast(float, v);
}
__device__ __forceinline__ unsigned short f2bf(float f) {
    unsigned int u = __builtin_bit_cast(unsigned int, f);
    u += 0x7fffu + ((u >> 16) & 1u);
    return (unsigned short)(u >> 16);
}

#define L_DIM 2304
#define D_DIM 512

// ---------------------------------------------------------------------------
// Kernel D: detect input dtype. Samples even-index uint16s of x. For bf16
// N(0,1) data the exponent field never reaches 0xC0 (|v| >= 2^65); for fp32
// data the even uint16s are low mantissa bits (uniform exponent) and hit it
// ~25% of the time. flag=1 -> fp32 inputs/outputs, flag=0 -> bf16.
// ---------------------------------------------------------------------------
__global__ void k_detect(const unsigned short* __restrict__ xs, int* __restrict__ flag) {
    int lane = threadIdx.x;  // 64 threads
    int cnt = 0;
#pragma unroll
    for (int j = 0; j < 16; j++) {
        unsigned short u = xs[2 * (lane * 16 + j)];
        int e = (u >> 7) & 0xFF;
        cnt += (e >= 0xC0) ? 1 : 0;
    }
#pragma unroll
    for (int m = 1; m < 64; m <<= 1) cnt += __shfl_xor(cnt, m);
    if (lane == 0) *flag = (cnt > 4) ? 1 : 0;
}

// ---------------------------------------------------------------------------
// Kernel C: convert an array (fp32 or bf16 per flag) to bf16. 8 elems/thread.
// ---------------------------------------------------------------------------
__global__ __launch_bounds__(256) void k_cvt(const void* __restrict__ src,
                                             short* __restrict__ dst, int count,
                                             const int* __restrict__ flag) {
    int i = (blockIdx.x * 256 + threadIdx.x) * 8;
    if (i >= count) return;
    if (*flag) {
        const float* s = (const float*)src + i;
        short8 o;
#pragma unroll
        for (int j = 0; j < 8; j++) o[j] = (short)f2bf(s[j]);
        *(short8*)(dst + i) = o;
    } else {
        *(short8*)(dst + i) = *(const short8*)((const short*)src + i);
    }
}

// ---------------------------------------------------------------------------
// Kernel 0: transpose x (N, D, L) -> flatX (N, L, D) bf16, 64x64 LDS tiles.
// grid (36, 8, 8), 256 threads. Dual load path per flag.
// ---------------------------------------------------------------------------
__global__ __launch_bounds__(256) void k_transpose(const void* __restrict__ x_,
                                                   short* __restrict__ fx,
                                                   const int* __restrict__ flag) {
    __shared__ __align__(16) short t[64 * 72];
    const int n = blockIdx.z, d0 = blockIdx.y * 64, l0 = blockIdx.x * 64;
    const int tid = threadIdx.x;
    if (*flag) {
        const float* x = (const float*)x_;
#pragma unroll
        for (int p = 0; p < 4; p++) {
            int i = tid + p * 256;
            int dr = i >> 4, lc = (i & 15) * 4;
            floatx4 v = *(const floatx4*)(x + (size_t)(n * D_DIM + d0 + dr) * L_DIM + l0 + lc);
#pragma unroll
            for (int j = 0; j < 4; j++) t[(lc + j) * 72 + dr] = (short)f2bf(v[j]);
        }
    } else {
        const short* x = (const short*)x_;
#pragma unroll
        for (int p = 0; p < 2; p++) {
            int i = tid + p * 256;
            int dr = i >> 3, lc = (i & 7) * 8;
            short8 v = *(const short8*)(x + (size_t)(n * D_DIM + d0 + dr) * L_DIM + l0 + lc);
#pragma unroll
            for (int j = 0; j < 8; j++) t[(lc + j) * 72 + dr] = v[j];
        }
    }
    __syncthreads();
#pragma unroll
    for (int p = 0; p < 2; p++) {
        int i = tid + p * 256;
        int lr = i >> 3, dc = (i & 7) * 8;
        short8 v = *(const short8*)&t[lr * 72 + dc];
        *(short8*)(fx + (size_t)(n * L_DIM + l0 + lr) * D_DIM + d0 + dc) = v;
    }
}

// ---------------------------------------------------------------------------
// Kernel 1: P = tanh(flatX @ W^T + b) for q/k/v (all bf16 now). 128x128 tile,
// BK=32, 256 threads = 4 waves (2x2), each wave 4x4 16x16x32 MFMA tiles.
// grid (72, 3, 8)
// ---------------------------------------------------------------------------
__global__ __launch_bounds__(256) void k_proj(const short* __restrict__ fx,
                                              const short* __restrict__ Wc,
                                              const short* __restrict__ bc,
                                              short* __restrict__ Pbase) {
    __shared__ __align__(16) short ldsA[128 * 40];
    __shared__ __align__(16) short ldsB[128 * 40];
    const int proj = blockIdx.y, n = blockIdx.z;
    const short* W = Wc + (size_t)proj * 262144;
    const short* bias = bc + proj * 512;
    short* P = Pbase + (size_t)proj * 8 * L_DIM * D_DIM + (size_t)n * L_DIM * D_DIM;
    const int l0 = (blockIdx.x >> 2) * 128, f0 = (blockIdx.x & 3) * 128;
    const int tid = threadIdx.x, lane = tid & 63, wid = tid >> 6;
    const int wm = wid & 1, wn = wid >> 1, quad = lane >> 4, l16 = lane & 15;
    const short* Abase = fx + (size_t)n * L_DIM * D_DIM;

    floatx4 acc[4][4] = {};
    for (int k0 = 0; k0 < 512; k0 += 32) {
        __syncthreads();
#pragma unroll
        for (int p = 0; p < 2; p++) {
            int i = tid + p * 256;
            int row = i >> 2, c = (i & 3) * 8;
            *(short8*)&ldsA[row * 40 + c] =
                *(const short8*)(Abase + (size_t)(l0 + row) * 512 + k0 + c);
            *(short8*)&ldsB[row * 40 + c] =
                *(const short8*)(W + (size_t)(f0 + row) * 512 + k0 + c);
        }
        __syncthreads();
        short8 a[4], b[4];
#pragma unroll
        for (int mi = 0; mi < 4; mi++)
            a[mi] = *(const short8*)&ldsA[(wm * 64 + mi * 16 + l16) * 40 + quad * 8];
#pragma unroll
        for (int ni = 0; ni < 4; ni++)
            b[ni] = *(const short8*)&ldsB[(wn * 64 + ni * 16 + l16) * 40 + quad * 8];
#pragma unroll
        for (int mi = 0; mi < 4; mi++)
#pragma unroll
            for (int ni = 0; ni < 4; ni++)
                acc[mi][ni] = __builtin_amdgcn_mfma_f32_16x16x32_bf16(a[mi], b[ni], acc[mi][ni], 0, 0, 0);
    }
#pragma unroll
    for (int ni = 0; ni < 4; ni++) {
        int f = f0 + wn * 64 + ni * 16 + l16;
        float bb = bf2f((unsigned short)bias[f & 511]);
#pragma unroll
        for (int mi = 0; mi < 4; mi++) {
#pragma unroll
            for (int r = 0; r < 4; r++) {
                int l = l0 + wm * 64 + mi * 16 + quad * 4 + r;
                float v = tanhf(acc[mi][ni][r] + bb);
                P[(size_t)l * 512 + f] = (short)f2bf(v);
            }
        }
    }
}

// ---------------------------------------------------------------------------
// Kernel 2: in-place double instance-norm over each 512-feature row.
// One wave per row; 55296 rows. grid 13824, 256 threads.
// ---------------------------------------------------------------------------
__global__ __launch_bounds__(256) void k_norm(short* __restrict__ base) {
    const int row = blockIdx.x * 4 + (threadIdx.x >> 6);
    const int lane = threadIdx.x & 63;
    short* p = base + (size_t)row * 512 + lane * 8;
    short8 v = *(const short8*)p;
    float x[8], s = 0.f, sq = 0.f;
#pragma unroll
    for (int j = 0; j < 8; j++) {
        x[j] = bf2f((unsigned short)v[j]);
        s += x[j];
        sq += x[j] * x[j];
    }
#pragma unroll
    for (int m = 1; m < 64; m <<= 1) {
        s += __shfl_xor(s, m);
        sq += __shfl_xor(sq, m);
    }
    float mu = s * (1.0f / 512.0f);
    float var = sq * (1.0f / 512.0f) - mu * mu;
    float r1 = rsqrtf(var + 1e-5f);
    float y[8], s2 = 0.f, sq2 = 0.f;
#pragma unroll
    for (int j = 0; j < 8; j++) {
        y[j] = (x[j] - mu) * r1;
        s2 += y[j];
        sq2 += y[j] * y[j];
    }
#pragma unroll
    for (int m = 1; m < 64; m <<= 1) {
        s2 += __shfl_xor(s2, m);
        sq2 += __shfl_xor(sq2, m);
    }
    float mu2 = s2 * (1.0f / 512.0f);
    float var2 = sq2 * (1.0f / 512.0f) - mu2 * mu2;
    float r2 = rsqrtf(var2 + 1e-5f);
    short8 o;
#pragma unroll
    for (int j = 0; j < 8; j++) o[j] = (short)f2bf((y[j] - mu2) * r2);
    *(short8*)p = o;
}

// ---------------------------------------------------------------------------
// Kernel 3: attention. Scores bounded by sqrt(512)=22.6 -> exp never
// overflows fp32: no max-subtraction / online rescale. Bq=64 q/block,
// Bk=32 keys/iter, 512 threads = 8 waves. Q frags in registers; K tile and
// V^T tile time-share one LDS buffer. Output dtype per flag. grid (36, 8).
// ---------------------------------------------------------------------------
__global__ __launch_bounds__(512) void k_attn(const short* __restrict__ Q,
                                              const short* __restrict__ K,
                                              const short* __restrict__ V,
                                              void* __restrict__ out_,
                                              const int* __restrict__ flag) {
    __shared__ __align__(16) short ldsKV[512 * 40];  // K tile 32x520 | VT tile 512x40
    __shared__ __align__(16) short ldsP[64 * 40];
    __shared__ float ldsL[64];
    const int n = blockIdx.y;
    const int q0 = blockIdx.x * 64;
    const int tid = threadIdx.x, lane = tid & 63, wid = tid >> 6;
    const int wq = wid & 3, wk = wid >> 2, quad = lane >> 4, l16 = lane & 15;
    const short* Qn = Q + (size_t)n * L_DIM * 512;
    const short* Kn = K + (size_t)n * L_DIM * 512;
    const short* Vn = V + (size_t)n * L_DIM * 512;
    if (tid < 64) ldsL[tid] = 0.f;

    short8 qf[16];
#pragma unroll
    for (int fs = 0; fs < 16; fs++)
        qf[fs] = *(const short8*)(Qn + (size_t)(q0 + wq * 16 + l16) * 512 + fs * 32 + quad * 8);

    floatx4 acc[16] = {};
    const float sc = 0.044194173824159216f;  // 1/sqrt(512)

    for (int kt = 0; kt < 72; kt++) {
        const int key0 = kt * 32;
        __syncthreads();  // protects ldsKV reuse + ldsL init on first iter
        // stage K tile (32 keys x 512 f), f-contiguous
#pragma unroll
        for (int p = 0; p < 4; p++) {
            int i = tid + p * 512;
            int row = i >> 6, c = (i & 63) * 8;
            *(short8*)&ldsKV[row * 520 + c] =
                *(const short8*)(Kn + (size_t)(key0 + row) * 512 + c);
        }
        __syncthreads();
        // S-phase: S[q][key] = sum_f Q K
        floatx4 sacc = {0.f, 0.f, 0.f, 0.f};
#pragma unroll
        for (int fs = 0; fs < 16; fs++) {
            short8 kf = *(const short8*)&ldsKV[(wk * 16 + l16) * 520 + fs * 32 + quad * 8];
            sacc = __builtin_amdgcn_mfma_f32_16x16x32_bf16(qf[fs], kf, sacc, 0, 0, 0);
        }
        float pe[4];
#pragma unroll
        for (int r = 0; r < 4; r++) {
            unsigned short pb = f2bf(__expf(sacc[r] * sc));
            ldsP[(wq * 16 + quad * 4 + r) * 40 + wk * 16 + l16] = (short)pb;
            pe[r] = bf2f(pb);  // denominator consistent with bf16-rounded P
        }
#pragma unroll
        for (int r = 0; r < 4; r++) {  // sum over 16 key-lanes, combine 2 waves
            float s = pe[r];
            s += __shfl_xor(s, 1);
            s += __shfl_xor(s, 2);
            s += __shfl_xor(s, 4);
            s += __shfl_xor(s, 8);
            if (l16 == 0) atomicAdd(&ldsL[wq * 16 + quad * 4 + r], s);
        }
        __syncthreads();  // K reads + P writes done -> overwrite ldsKV with VT
        // stage V^T (512 f x 32 keys)
#pragma unroll
        for (int p = 0; p < 4; p++) {
            int i = tid + p * 512;
            int row = i >> 6, c = (i & 63) * 8;
            short8 v = *(const short8*)(Vn + (size_t)(key0 + row) * 512 + c);
#pragma unroll
            for (int j = 0; j < 8; j++) ldsKV[(c + j) * 40 + row] = v[j];
        }
        __syncthreads();
        // PV-phase: O[q][f] += P[q][key] * V[key][f]
        short8 pf = *(const short8*)&ldsP[(wq * 16 + l16) * 40 + quad * 8];
#pragma unroll
        for (int ni = 0; ni < 16; ni++) {
            short8 vf = *(const short8*)&ldsKV[(wk * 256 + ni * 16 + l16) * 40 + quad * 8];
            acc[ni] = __builtin_amdgcn_mfma_f32_16x16x32_bf16(pf, vf, acc[ni], 0, 0, 0);
        }
    }
    __syncthreads();
    float rl[4];
#pragma unroll
    for (int r = 0; r < 4; r++) rl[r] = 1.0f / ldsL[wq * 16 + quad * 4 + r];
    if (*flag) {
        float* out = (float*)out_;
#pragma unroll
        for (int ni = 0; ni < 16; ni++) {
            int f = wk * 256 + ni * 16 + l16;
#pragma unroll
            for (int r = 0; r < 4; r++) {
                int q = q0 + wq * 16 + quad * 4 + r;
                out[((size_t)n * L_DIM + q) * 512 + f] = acc[ni][r] * rl[r];
            }
        }
    } else {
        short* out = (short*)out_;
#pragma unroll
        for (int ni = 0; ni < 16; ni++) {
            int f = wk * 256 + ni * 16 + l16;
#pragma unroll
            for (int r = 0; r < 4; r++) {
                int q = q0 + wq * 16 + quad * 4 + r;
                out[((size_t)n * L_DIM + q) * 512 + f] = (short)f2bf(acc[ni][r] * rl[r]);
            }
        }
    }
}

extern "C" void kernel_launch(void* const* d_in, const int* in_sizes, int n_in,
                              void* d_out, int out_size, void* d_ws, size_t ws_size,
                              hipStream_t stream) {
    char* ws = (char*)d_ws;
    const size_t S1 = (size_t)8 * L_DIM * D_DIM * sizeof(short);  // 18,874,368 B
    int* flag = (int*)ws;                                // @0
    short* Wc = (short*)(ws + 4096);                     // 3 * 512*512 bf16
    short* bc = (short*)(ws + 4096 + 3 * 262144 * 2);    // 3 * 512 bf16
    short* flatX = (short*)(ws + 4096 + 3 * 262144 * 2 + 4096);
    short* Pq = (short*)((char*)flatX + S1);
    short* Pk = (short*)((char*)Pq + S1);
    short* Pv = (short*)((char*)Pk + S1);

    k_detect<<<1, 64, 0, stream>>>((const unsigned short*)d_in[0], flag);
    k_cvt<<<128, 256, 0, stream>>>(d_in[1], Wc + 0 * 262144, 262144, flag);
    k_cvt<<<128, 256, 0, stream>>>(d_in[3], Wc + 1 * 262144, 262144, flag);
    k_cvt<<<128, 256, 0, stream>>>(d_in[5], Wc + 2 * 262144, 262144, flag);
    k_cvt<<<1, 256, 0, stream>>>(d_in[2], bc + 0, 512, flag);
    k_cvt<<<1, 256, 0, stream>>>(d_in[4], bc + 512, 512, flag);
    k_cvt<<<1, 256, 0, stream>>>(d_in[6], bc + 1024, 512, flag);
    k_transpose<<<dim3(36, 8, 8), 256, 0, stream>>>(d_in[0], flatX, flag);
    k_proj<<<dim3(72, 3, 8), 256, 0, stream>>>(flatX, Wc, bc, Pq);
    k_norm<<<13824, 256, 0, stream>>>(Pq);  // Q,K,V contiguous
    k_attn<<<dim3(36, 8), 512, 0, stream>>>(Pq, Pk, Pv, d_out, flag);
}

// Round 3
// 358.882 us; speedup vs baseline: 4.3094x; 4.3094x over previous
//
#include <hip/hip_runtime.h>

typedef __attribute__((ext_vector_type(8))) short short8;
typedef __attribute__((ext_vector_type(4))) short short4v;
typedef __attribute__((ext_vector_type(4))) float floatx4;

__device__ __forceinline__ float bf2f(unsigned short u) {
    unsigned int v = ((unsigned int)u) << 16;
    return __builtin_bit_cast(float, v);
}
__device__ __forceinline__ unsigned short f2bf(float f) {
    unsigned int u = __builtin_bit_cast(unsigned int, f);
    u += 0x7fffu + ((u >> 16) & 1u);
    return (unsigned short)(u >> 16);
}

// async global->LDS, 16 B per lane. LDS dest = wave-uniform base + lane*16.
__device__ __forceinline__ void gl_lds16(const void* g, void* l) {
    __builtin_amdgcn_global_load_lds(
        (const __attribute__((address_space(1))) unsigned int*)g,
        (__attribute__((address_space(3))) unsigned int*)l, 16, 0, 0);
}

#define L_DIM 2304
#define D_DIM 512

// ---------------------------------------------------------------------------
// Kernel D: detect input dtype (fp32 vs bf16) from exponent-field statistics.
// ---------------------------------------------------------------------------
__global__ void k_detect(const unsigned short* __restrict__ xs, int* __restrict__ flag) {
    int lane = threadIdx.x;  // 64 threads
    int cnt = 0;
#pragma unroll
    for (int j = 0; j < 16; j++) {
        unsigned short u = xs[2 * (lane * 16 + j)];
        int e = (u >> 7) & 0xFF;
        cnt += (e >= 0xC0) ? 1 : 0;
    }
#pragma unroll
    for (int m = 1; m < 64; m <<= 1) cnt += __shfl_xor(cnt, m);
    if (lane == 0) *flag = (cnt > 4) ? 1 : 0;
}

// ---------------------------------------------------------------------------
// Kernel C: convert array (fp32 or bf16 per flag) to bf16.
// ---------------------------------------------------------------------------
__global__ __launch_bounds__(256) void k_cvt(const void* __restrict__ src,
                                             short* __restrict__ dst, int count,
                                             const int* __restrict__ flag) {
    int i = (blockIdx.x * 256 + threadIdx.x) * 8;
    if (i >= count) return;
    if (*flag) {
        const float* s = (const float*)src + i;
        short8 o;
#pragma unroll
        for (int j = 0; j < 8; j++) o[j] = (short)f2bf(s[j]);
        *(short8*)(dst + i) = o;
    } else {
        *(short8*)(dst + i) = *(const short8*)((const short*)src + i);
    }
}

// ---------------------------------------------------------------------------
// Kernel 0: transpose x (N, D, L) -> flatX (N, L, D) bf16, 64x64 LDS tiles.
// ---------------------------------------------------------------------------
__global__ __launch_bounds__(256) void k_transpose(const void* __restrict__ x_,
                                                   short* __restrict__ fx,
                                                   const int* __restrict__ flag) {
    __shared__ __align__(16) short t[64 * 72];
    const int n = blockIdx.z, d0 = blockIdx.y * 64, l0 = blockIdx.x * 64;
    const int tid = threadIdx.x;
    if (*flag) {
        const float* x = (const float*)x_;
#pragma unroll
        for (int p = 0; p < 4; p++) {
            int i = tid + p * 256;
            int dr = i >> 4, lc = (i & 15) * 4;
            floatx4 v = *(const floatx4*)(x + (size_t)(n * D_DIM + d0 + dr) * L_DIM + l0 + lc);
#pragma unroll
            for (int j = 0; j < 4; j++) t[(lc + j) * 72 + dr] = (short)f2bf(v[j]);
        }
    } else {
        const short* x = (const short*)x_;
#pragma unroll
        for (int p = 0; p < 2; p++) {
            int i = tid + p * 256;
            int dr = i >> 3, lc = (i & 7) * 8;
            short8 v = *(const short8*)(x + (size_t)(n * D_DIM + d0 + dr) * L_DIM + l0 + lc);
#pragma unroll
            for (int j = 0; j < 8; j++) t[(lc + j) * 72 + dr] = v[j];
        }
    }
    __syncthreads();
#pragma unroll
    for (int p = 0; p < 2; p++) {
        int i = tid + p * 256;
        int lr = i >> 3, dc = (i & 7) * 8;
        short8 v = *(const short8*)&t[lr * 72 + dc];
        *(short8*)(fx + (size_t)(n * L_DIM + l0 + lr) * D_DIM + d0 + dc) = v;
    }
}

// ---------------------------------------------------------------------------
// Kernel TV: transpose V (N, L, F) -> Vt (N, F, L). Tile f64 x l64.
// Thread: 4 l-rows x 8 f; LDS writes are packed short4 (b64), lane-major in l
// so banks spread over l (2-way, free). grid (36, 8, 8), 256 thr.
// ---------------------------------------------------------------------------
__global__ __launch_bounds__(256) void k_trV(const short* __restrict__ src,
                                             short* __restrict__ dst) {
    __shared__ __align__(16) short t[64 * 72];
    const int n = blockIdx.z, l0 = blockIdx.x * 64, f0 = blockIdx.y * 64;
    const int tid = threadIdx.x;
    const int lo4 = (tid & 15) * 4;       // l offset 0..60 (lane-varying -> bank spread)
    const int fo = (tid >> 4) * 8;        // hmm: tid>>4 in 0..15 -> f offset 0..120? cap:
    // 256 threads: (tid&15) -> 16 l-groups, (tid>>4) -> 16 f-chunks of 8? f-span is 64,
    // so use 8 f-chunks and 2 l-halves: remap:
    const int fo8 = ((tid >> 4) & 7) * 8;          // f offset 0..56
    const int lo = lo4 + ((tid >> 7) & 1) * 0;     // keep 64 l via 16*4 = 64 -> ok
    // thread covers rows l0+lo..+3, cols f0+fo8..+7 ; top half threads (tid>=128) do same
    // with second half of... simpler: two passes p over f handled below.
    short8 v[4];
#pragma unroll
    for (int p = 0; p < 1; p++) { }
    // load 4 l-rows x 8 f (only threads' unique (lo4, fo8, tid>>7) combos):
    // use tid bit 7 to split f range: fo_final in 0..56 (+ 0 or 0) -- f-span 64 needs 8 chunks,
    // 16 lanes l x 8 f-chunks x (4 l-rows each covering 64 l) = 128 threads; run 2 l-tiles:
    const int lsub = (tid >> 7) * 0;  // unused
    if (tid < 128) {
        const int ll = (tid & 15) * 4;
        const int ff = (tid >> 4) * 8;
#pragma unroll
        for (int r = 0; r < 4; r++)
            v[r] = *(const short8*)(src + (size_t)(n * L_DIM + l0 + ll + r) * D_DIM + f0 + ff);
#pragma unroll
        for (int j = 0; j < 8; j++) {
            short4v w = { v[0][j], v[1][j], v[2][j], v[3][j] };
            *(short4v*)&t[(ff + j) * 72 + ll] = w;
        }
    }
    __syncthreads();
    // store: 8 f-rows per pass, 128B contiguous l per row segment
#pragma unroll
    for (int p = 0; p < 2; p++) {
        int i = tid + p * 256;
        int fr = i >> 3, lc = (i & 7) * 8;
        short8 o = *(const short8*)&t[fr * 72 + lc];
        *(short8*)(dst + (size_t)(n * D_DIM + f0 + fr) * L_DIM + l0 + lc) = o;
    }
}

// ---------------------------------------------------------------------------
// Shared GEMM core: C(128x128) = A(M x K) * B^T(N x K), bf16, BK=32,
// 256 threads = 4 waves (2x2), wave = 64x64 = 4x4 16x16x32 MFMA.
// Staging via global_load_lds width 16; LDS tiles unpadded 128x32.
// ---------------------------------------------------------------------------
__device__ __forceinline__ void gemm128(const short* __restrict__ A,
                                        const short* __restrict__ B,
                                        int K, int l0, int f0,
                                        short* ldsA, short* ldsB,
                                        floatx4 acc[4][4]) {
    const int tid = threadIdx.x, lane = tid & 63, wid = tid >> 6;
    const int wm = wid & 1, wn = wid >> 1, quad = lane >> 4, l16 = lane & 15;
    const int r16 = lane >> 2, c8 = (lane & 3) * 8;
    for (int kt = 0; kt < K; kt += 32) {
        __syncthreads();
#pragma unroll
        for (int p = 0; p < 2; p++) {
            int row = (wid + p * 4) * 16;
            gl_lds16(A + (size_t)(l0 + row + r16) * K + kt + c8, ldsA + row * 32);
            gl_lds16(B + (size_t)(f0 + row + r16) * K + kt + c8, ldsB + row * 32);
        }
        __syncthreads();
        short8 a[4], b[4];
#pragma unroll
        for (int mi = 0; mi < 4; mi++)
            a[mi] = *(const short8*)&ldsA[(wm * 64 + mi * 16 + l16) * 32 + quad * 8];
#pragma unroll
        for (int ni = 0; ni < 4; ni++)
            b[ni] = *(const short8*)&ldsB[(wn * 64 + ni * 16 + l16) * 32 + quad * 8];
#pragma unroll
        for (int mi = 0; mi < 4; mi++)
#pragma unroll
            for (int ni = 0; ni < 4; ni++)
                acc[mi][ni] = __builtin_amdgcn_mfma_f32_16x16x32_bf16(a[mi], b[ni], acc[mi][ni], 0, 0, 0);
    }
}

// ---------------------------------------------------------------------------
// Kernel 1: P = tanh(flatX @ W^T + b). grid (72, 3, 8).
// ---------------------------------------------------------------------------
__global__ __launch_bounds__(256) void k_gemm_proj(const short* __restrict__ fx,
                                                   const short* __restrict__ Wc,
                                                   const short* __restrict__ bc,
                                                   short* __restrict__ Pbase) {
    __shared__ __align__(16) short ldsA[128 * 32];
    __shared__ __align__(16) short ldsB[128 * 32];
    const int proj = blockIdx.y, n = blockIdx.z;
    const int l0 = (blockIdx.x >> 2) * 128, f0 = (blockIdx.x & 3) * 128;
    const short* A = fx + (size_t)n * L_DIM * D_DIM;
    const short* B = Wc + (size_t)proj * 262144;
    const short* bias = bc + proj * 512;
    short* P = Pbase + (size_t)proj * 8 * L_DIM * D_DIM + (size_t)n * L_DIM * D_DIM;
    const int lane = threadIdx.x & 63, wid = threadIdx.x >> 6;
    const int wm = wid & 1, wn = wid >> 1, quad = lane >> 4, l16 = lane & 15;

    floatx4 acc[4][4] = {};
    gemm128(A, B, 512, l0, f0, ldsA, ldsB, acc);

#pragma unroll
    for (int ni = 0; ni < 4; ni++) {
        int f = f0 + wn * 64 + ni * 16 + l16;
        float bb = bf2f((unsigned short)bias[f]);
#pragma unroll
        for (int mi = 0; mi < 4; mi++) {
#pragma unroll
            for (int r = 0; r < 4; r++) {
                int l = l0 + wm * 64 + mi * 16 + quad * 4 + r;
                float v = tanhf(acc[mi][ni][r] + bb);
                P[(size_t)l * 512 + f] = (short)f2bf(v);
            }
        }
    }
}

// ---------------------------------------------------------------------------
// Kernel 2: in-place double instance-norm over each 512-feature row.
// ---------------------------------------------------------------------------
__global__ __launch_bounds__(256) void k_norm(short* __restrict__ base) {
    const int row = blockIdx.x * 4 + (threadIdx.x >> 6);
    const int lane = threadIdx.x & 63;
    short* p = base + (size_t)row * 512 + lane * 8;
    short8 v = *(const short8*)p;
    float x[8], s = 0.f, sq = 0.f;
#pragma unroll
    for (int j = 0; j < 8; j++) {
        x[j] = bf2f((unsigned short)v[j]);
        s += x[j];
        sq += x[j] * x[j];
    }
#pragma unroll
    for (int m = 1; m < 64; m <<= 1) {
        s += __shfl_xor(s, m);
        sq += __shfl_xor(sq, m);
    }
    float mu = s * (1.0f / 512.0f);
    float var = sq * (1.0f / 512.0f) - mu * mu;
    float r1 = rsqrtf(var + 1e-5f);
    float y[8], s2 = 0.f, sq2 = 0.f;
#pragma unroll
    for (int j = 0; j < 8; j++) {
        y[j] = (x[j] - mu) * r1;
        s2 += y[j];
        sq2 += y[j] * y[j];
    }
#pragma unroll
    for (int m = 1; m < 64; m <<= 1) {
        s2 += __shfl_xor(s2, m);
        sq2 += __shfl_xor(sq2, m);
    }
    float mu2 = s2 * (1.0f / 512.0f);
    float var2 = sq2 * (1.0f / 512.0f) - mu2 * mu2;
    float r2 = rsqrtf(var2 + 1e-5f);
    short8 o;
#pragma unroll
    for (int j = 0; j < 8; j++) o[j] = (short)f2bf((y[j] - mu2) * r2);
    *(short8*)p = o;
}

// ---------------------------------------------------------------------------
// Kernel 3a: P = exp(Q K^T / sqrt(512)) bf16 + row-sum atomics.
// grid (324, 8): 18x18 M/N tiles per n.
// ---------------------------------------------------------------------------
__global__ __launch_bounds__(256) void k_gemm_scores(const short* __restrict__ Q,
                                                     const short* __restrict__ Kb,
                                                     short* __restrict__ P,
                                                     float* __restrict__ lsum) {
    __shared__ __align__(16) short ldsA[128 * 32];
    __shared__ __align__(16) short ldsB[128 * 32];
    const int n = blockIdx.y;
    const int l0 = (blockIdx.x / 18) * 128, m0 = (blockIdx.x % 18) * 128;
    const short* A = Q + (size_t)n * L_DIM * D_DIM;
    const short* B = Kb + (size_t)n * L_DIM * D_DIM;
    const int lane = threadIdx.x & 63, wid = threadIdx.x >> 6;
    const int wm = wid & 1, wn = wid >> 1, quad = lane >> 4, l16 = lane & 15;

    floatx4 acc[4][4] = {};
    gemm128(A, B, 512, l0, m0, ldsA, ldsB, acc);

    const float sc = 0.044194173824159216f;  // 1/sqrt(512)
    short* Pn = P + (size_t)n * L_DIM * L_DIM;
    float* ln = lsum + n * L_DIM;
#pragma unroll
    for (int mi = 0; mi < 4; mi++) {
#pragma unroll
        for (int r = 0; r < 4; r++) {
            int row = l0 + wm * 64 + mi * 16 + quad * 4 + r;
            float s = 0.f;
#pragma unroll
            for (int ni = 0; ni < 4; ni++) {
                int col = m0 + wn * 64 + ni * 16 + l16;
                unsigned short pb = f2bf(__expf(acc[mi][ni][r] * sc));
                Pn[(size_t)row * L_DIM + col] = (short)pb;
                s += bf2f(pb);  // denominator consistent with bf16-rounded P
            }
            s += __shfl_xor(s, 1);
            s += __shfl_xor(s, 2);
            s += __shfl_xor(s, 4);
            s += __shfl_xor(s, 8);
            if (l16 == 0) atomicAdd(&ln[row], s);
        }
    }
}

// ---------------------------------------------------------------------------
// Kernel 3b: out = (P @ V) / lsum. grid (72, 8): 18 M-tiles x 4 N-tiles per n.
// B operand = Vt (F x L).
// ---------------------------------------------------------------------------
__global__ __launch_bounds__(256) void k_gemm_out(const short* __restrict__ P,
                                                  const short* __restrict__ Vt,
                                                  const float* __restrict__ lsum,
                                                  void* __restrict__ out_,
                                                  const int* __restrict__ flag) {
    __shared__ __align__(16) short ldsA[128 * 32];
    __shared__ __align__(16) short ldsB[128 * 32];
    const int n = blockIdx.y;
    const int l0 = (blockIdx.x >> 2) * 128, f0 = (blockIdx.x & 3) * 128;
    const short* A = P + (size_t)n * L_DIM * L_DIM;
    const short* B = Vt + (size_t)n * D_DIM * L_DIM;
    const int lane = threadIdx.x & 63, wid = threadIdx.x >> 6;
    const int wm = wid & 1, wn = wid >> 1, quad = lane >> 4, l16 = lane & 15;

    floatx4 acc[4][4] = {};
    gemm128(A, B, L_DIM, l0, f0, ldsA, ldsB, acc);

    const int fl = *flag;
#pragma unroll
    for (int mi = 0; mi < 4; mi++) {
#pragma unroll
        for (int r = 0; r < 4; r++) {
            int row = l0 + wm * 64 + mi * 16 + quad * 4 + r;
            float rl = 1.0f / lsum[n * L_DIM + row];
            if (fl) {
                float* out = (float*)out_;
#pragma unroll
                for (int ni = 0; ni < 4; ni++) {
                    int f = f0 + wn * 64 + ni * 16 + l16;
                    out[((size_t)n * L_DIM + row) * 512 + f] = acc[mi][ni][r] * rl;
                }
            } else {
                short* out = (short*)out_;
#pragma unroll
                for (int ni = 0; ni < 4; ni++) {
                    int f = f0 + wn * 64 + ni * 16 + l16;
                    out[((size_t)n * L_DIM + row) * 512 + f] = (short)f2bf(acc[mi][ni][r] * rl);
                }
            }
        }
    }
}

// ---------------------------------------------------------------------------
// FALLBACK fused attention (round-2 version, known correct) for small ws.
// ---------------------------------------------------------------------------
__global__ __launch_bounds__(512) void k_attn(const short* __restrict__ Q,
                                              const short* __restrict__ K,
                                              const short* __restrict__ V,
                                              void* __restrict__ out_,
                                              const int* __restrict__ flag) {
    __shared__ __align__(16) short ldsKV[512 * 40];
    __shared__ __align__(16) short ldsP[64 * 40];
    __shared__ float ldsL[64];
    const int n = blockIdx.y;
    const int q0 = blockIdx.x * 64;
    const int tid = threadIdx.x, lane = tid & 63, wid = tid >> 6;
    const int wq = wid & 3, wk = wid >> 2, quad = lane >> 4, l16 = lane & 15;
    const short* Qn = Q + (size_t)n * L_DIM * 512;
    const short* Kn = K + (size_t)n * L_DIM * 512;
    const short* Vn = V + (size_t)n * L_DIM * 512;
    if (tid < 64) ldsL[tid] = 0.f;

    short8 qf[16];
#pragma unroll
    for (int fs = 0; fs < 16; fs++)
        qf[fs] = *(const short8*)(Qn + (size_t)(q0 + wq * 16 + l16) * 512 + fs * 32 + quad * 8);

    floatx4 acc[16] = {};
    const float sc = 0.044194173824159216f;

    for (int kt = 0; kt < 72; kt++) {
        const int key0 = kt * 32;
        __syncthreads();
#pragma unroll
        for (int p = 0; p < 4; p++) {
            int i = tid + p * 512;
            int row = i >> 6, c = (i & 63) * 8;
            *(short8*)&ldsKV[row * 520 + c] =
                *(const short8*)(Kn + (size_t)(key0 + row) * 512 + c);
        }
        __syncthreads();
        floatx4 sacc = {0.f, 0.f, 0.f, 0.f};
#pragma unroll
        for (int fs = 0; fs < 16; fs++) {
            short8 kf = *(const short8*)&ldsKV[(wk * 16 + l16) * 520 + fs * 32 + quad * 8];
            sacc = __builtin_amdgcn_mfma_f32_16x16x32_bf16(qf[fs], kf, sacc, 0, 0, 0);
        }
        float pe[4];
#pragma unroll
        for (int r = 0; r < 4; r++) {
            unsigned short pb = f2bf(__expf(sacc[r] * sc));
            ldsP[(wq * 16 + quad * 4 + r) * 40 + wk * 16 + l16] = (short)pb;
            pe[r] = bf2f(pb);
        }
#pragma unroll
        for (int r = 0; r < 4; r++) {
            float s = pe[r];
            s += __shfl_xor(s, 1);
            s += __shfl_xor(s, 2);
            s += __shfl_xor(s, 4);
            s += __shfl_xor(s, 8);
            if (l16 == 0) atomicAdd(&ldsL[wq * 16 + quad * 4 + r], s);
        }
        __syncthreads();
#pragma unroll
        for (int p = 0; p < 4; p++) {
            int i = tid + p * 512;
            int row = i >> 6, c = (i & 63) * 8;
            short8 v = *(const short8*)(Vn + (size_t)(key0 + row) * 512 + c);
#pragma unroll
            for (int j = 0; j < 8; j++) ldsKV[(c + j) * 40 + row] = v[j];
        }
        __syncthreads();
        short8 pf = *(const short8*)&ldsP[(wq * 16 + l16) * 40 + quad * 8];
#pragma unroll
        for (int ni = 0; ni < 16; ni++) {
            short8 vf = *(const short8*)&ldsKV[(wk * 256 + ni * 16 + l16) * 40 + quad * 8];
            acc[ni] = __builtin_amdgcn_mfma_f32_16x16x32_bf16(pf, vf, acc[ni], 0, 0, 0);
        }
    }
    __syncthreads();
    float rl[4];
#pragma unroll
    for (int r = 0; r < 4; r++) rl[r] = 1.0f / ldsL[wq * 16 + quad * 4 + r];
    if (*flag) {
        float* out = (float*)out_;
#pragma unroll
        for (int ni = 0; ni < 16; ni++) {
            int f = wk * 256 + ni * 16 + l16;
#pragma unroll
            for (int r = 0; r < 4; r++) {
                int q = q0 + wq * 16 + quad * 4 + r;
                out[((size_t)n * L_DIM + q) * 512 + f] = acc[ni][r] * rl[r];
            }
        }
    } else {
        short* out = (short*)out_;
#pragma unroll
        for (int ni = 0; ni < 16; ni++) {
            int f = wk * 256 + ni * 16 + l16;
#pragma unroll
            for (int r = 0; r < 4; r++) {
                int q = q0 + wq * 16 + quad * 4 + r;
                out[((size_t)n * L_DIM + q) * 512 + f] = (short)f2bf(acc[ni][r] * rl[r]);
            }
        }
    }
}

extern "C" void kernel_launch(void* const* d_in, const int* in_sizes, int n_in,
                              void* d_out, int out_size, void* d_ws, size_t ws_size,
                              hipStream_t stream) {
    char* ws = (char*)d_ws;
    const size_t S1 = (size_t)8 * L_DIM * D_DIM * sizeof(short);  // 18,874,368
    int* flag = (int*)ws;
    short* Wc = (short*)(ws + 4096);
    short* bc = (short*)(ws + 4096 + 3 * 262144 * 2);
    short* flatX = (short*)(ws + 1581056);
    short* Pq = (short*)((char*)flatX + S1);
    short* Pk = (short*)((char*)Pq + S1);
    short* Pv = (short*)((char*)Pk + S1);

    k_detect<<<1, 64, 0, stream>>>((const unsigned short*)d_in[0], flag);
    k_cvt<<<128, 256, 0, stream>>>(d_in[1], Wc + 0 * 262144, 262144, flag);
    k_cvt<<<128, 256, 0, stream>>>(d_in[3], Wc + 1 * 262144, 262144, flag);
    k_cvt<<<128, 256, 0, stream>>>(d_in[5], Wc + 2 * 262144, 262144, flag);
    k_cvt<<<1, 256, 0, stream>>>(d_in[2], bc + 0, 512, flag);
    k_cvt<<<1, 256, 0, stream>>>(d_in[4], bc + 512, 512, flag);
    k_cvt<<<1, 256, 0, stream>>>(d_in[6], bc + 1024, 512, flag);
    k_transpose<<<dim3(36, 8, 8), 256, 0, stream>>>(d_in[0], flatX, flag);
    k_gemm_proj<<<dim3(72, 3, 8), 256, 0, stream>>>(flatX, Wc, bc, Pq);
    k_norm<<<13824, 256, 0, stream>>>(Pq);  // Q,K,V contiguous

    const size_t need = 1581056 + 5 * S1 + 73728 + (size_t)8 * L_DIM * L_DIM * 2;
    if (ws_size >= need) {
        short* Vt = (short*)((char*)Pv + S1);
        float* lsum = (float*)((char*)Vt + S1);
        short* P = (short*)((char*)lsum + 73728);
        k_trV<<<dim3(36, 8, 8), 256, 0, stream>>>(Pv, Vt);
        hipMemsetAsync(lsum, 0, 8 * L_DIM * sizeof(float), stream);
        k_gemm_scores<<<dim3(324, 8), 256, 0, stream>>>(Pq, Pk, P, lsum);
        k_gemm_out<<<dim3(72, 8), 256, 0, stream>>>(P, Vt, lsum, d_out, flag);
    } else {
        k_attn<<<dim3(36, 8), 512, 0, stream>>>(Pq, Pk, Pv, d_out, flag);
    }
}